// Round 1
// 341.178 us; speedup vs baseline: 1.0097x; 1.0097x over previous
//
#include <hip/hip_runtime.h>

#define ORDER 24
#define W 25                    // row width = ORDER + 1
#define ROWS_PER_BLOCK 256
#define THREADS 256
#define WAVE_FLOATS (64 * W)    // 1600 floats = 6400 B per wave (wave-private)

// Levinson recursion: PARCOR (reflection) -> LPC coefficients, one thread/row.
// a[m] is unmodified before step m, so k[m] == a[m] on entry to step m.
__device__ __forceinline__ void levinson(float* __restrict__ a)
{
    #pragma unroll
    for (int m = 2; m <= ORDER; ++m) {
        const float km = a[m];
        #pragma unroll
        for (int j = 1; j <= (m - 1) / 2; ++j) {
            const float lo = a[j], hi = a[m - j];
            a[j]     = fmaf(km, hi, lo);
            a[m - j] = fmaf(km, lo, hi);
        }
        if ((m & 1) == 0) {                 // self-paired middle element
            const float v = a[m / 2];
            a[m / 2] = fmaf(km, v, v);
        }
    }
}

// Wave-autonomous streaming version:
//  - each wave64 owns 64 rows = 6400 B of contiguous LDS (wave-private slice)
//  - stage-in is direct HBM->LDS DMA (global_load_lds, 6x1024B + 1x256B),
//    completion via this wave's vmcnt only -> NO __syncthreads anywhere
//  - per-thread row access at stride 25 floats (odd) = 2 lanes/bank = free
//  - stage-out is float4-coalesced LDS->global from the wave's own slice
__global__ __launch_bounds__(THREADS)
void parcor2lpc_kernel(const float* __restrict__ in,
                       float* __restrict__ out, int rows)
{
    __shared__ __align__(16) float lds[ROWS_PER_BLOCK * W];   // 25.6 KB -> 6 blocks/CU

    const int t    = threadIdx.x;
    const int wave = t >> 6;
    const int lane = t & 63;
    const long long row0 = (long long)blockIdx.x * ROWS_PER_BLOCK;
    const long long base = row0 * W;        // float offset of block chunk (16B aligned)
    const long long rem  = (long long)rows - row0;
    const int nrows = rem >= ROWS_PER_BLOCK ? ROWS_PER_BLOCK : (int)rem;

    if (nrows == ROWS_PER_BLOCK) {
        // ---------------- fast path: barrier-free ----------------
        const int wbase = wave * WAVE_FLOATS;            // wave-uniform
        const float* __restrict__ gw = in + base + wbase;

        // 6 chunks of 1024 B: lane l writes LDS at (uniform base) + l*16
        #pragma unroll
        for (int k = 0; k < 6; ++k) {
            __builtin_amdgcn_global_load_lds(
                (const __attribute__((address_space(1))) void*)(gw + k * 256 + lane * 4),
                (__attribute__((address_space(3))) void*)(&lds[wbase + k * 256]),
                16, 0, 0);
        }
        // tail 256 B (64 floats), width 4
        __builtin_amdgcn_global_load_lds(
            (const __attribute__((address_space(1))) void*)(gw + 1536 + lane),
            (__attribute__((address_space(3))) void*)(&lds[wbase + 1536]),
            4, 0, 0);

        // wait for OUR wave's DMA only; LDS slice is wave-private
        asm volatile("s_waitcnt vmcnt(0)" ::: "memory");

        float a[W];
        #pragma unroll
        for (int j = 0; j < W; ++j) a[j] = lds[t * W + j];

        levinson(a);

        // write back into the wave's own slice (no cross-wave readers)
        #pragma unroll
        for (int j = 0; j < W; ++j) lds[t * W + j] = a[j];

        // stage-out: 400 float4 per wave = 6 full rounds + 16-lane tail
        float4* __restrict__ gout = (float4*)(out + base);
        const float4* sv = (const float4*)lds;
        const int f0 = wave * (WAVE_FLOATS / 4);         // 400 float4 / wave
        #pragma unroll
        for (int k = 0; k < 6; ++k)
            gout[f0 + k * 64 + lane] = sv[f0 + k * 64 + lane];
        if (lane < 16)
            gout[f0 + 384 + lane] = sv[f0 + 384 + lane];
    } else {
        // ---------------- generic tail block (not hit at benched size) ----------------
        for (int i = t; i < nrows * W; i += THREADS)
            lds[i] = in[base + i];
        __syncthreads();
        if (t < nrows) {
            float a[W];
            for (int j = 0; j < W; ++j) a[j] = lds[t * W + j];
            levinson(a);
            for (int j = 0; j < W; ++j) lds[t * W + j] = a[j];
        }
        __syncthreads();
        for (int i = t; i < nrows * W; i += THREADS)
            out[base + i] = lds[i];
    }
}

extern "C" void kernel_launch(void* const* d_in, const int* in_sizes, int n_in,
                              void* d_out, int out_size, void* d_ws, size_t ws_size,
                              hipStream_t stream) {
    const float* k = (const float*)d_in[0];
    float* out = (float*)d_out;
    const int rows = in_sizes[0] / W;                 // 2,097,152
    const int grid = (rows + ROWS_PER_BLOCK - 1) / ROWS_PER_BLOCK;  // 8192
    parcor2lpc_kernel<<<grid, THREADS, 0, stream>>>(k, out, rows);
}